// Round 2
// baseline (2097.796 us; speedup 1.0000x reference)
//
#include <hip/hip_runtime.h>
#include <hip/hip_bf16.h>

typedef __bf16 bf16;
typedef __attribute__((ext_vector_type(8))) __bf16 bf16x8;
typedef __attribute__((ext_vector_type(4))) float f32x4;

// ---------------------------------------------------------------------------
// A-fragment loader: 8 contiguous K elements per lane; source f32 or bf16.
// ---------------------------------------------------------------------------
template<bool F>
__device__ inline bf16x8 load_frag(const void* A, long row, int kc) {
  if constexpr (F) {
    const float* p = (const float*)A + row * 128 + kc;
    f32x4 x0 = *(const f32x4*)p;
    f32x4 x1 = *(const f32x4*)(p + 4);
    bf16x8 r;
#pragma unroll
    for (int i = 0; i < 4; ++i) { r[i] = (bf16)x0[i]; r[i + 4] = (bf16)x1[i]; }
    return r;
  } else {
    return *(const bf16x8*)((const bf16*)A + row * 128 + kc);
  }
}

// ---------------------------------------------------------------------------
// MFMA GEMM: acc[M x ncols] = A1[M x 128] @ W1^T (+ A2 @ W2^T) + bias1(+bias2)
// W row-major [n_out x ldw]; K fixed 128. Block 256 thr = 4 waves,
// tile 128 rows x 128 cols (per blockIdx.y).
// EPI 0: C[row*ldc + n] = bf16(acc + bias)
// EPI 1: GRU finish (ncols=128): nn = tanh(acc + bias + tmp[row,n]);
//        z = sigmoid(srz[row,128+n]); h32[row,n] = (1-z)*nn + z*h32[row,n]
// ---------------------------------------------------------------------------
template<bool A1F, bool A2F, int EPI>
__global__ __launch_bounds__(256) void gemm_k(
    const void* __restrict__ A1, const bf16* __restrict__ W1, int ldw1,
    const void* __restrict__ A2, const bf16* __restrict__ W2, int ldw2,
    const bf16* __restrict__ bias1, const bf16* __restrict__ bias2,
    bf16* __restrict__ C, int ldc, int M,
    const bf16* __restrict__ tmp, const bf16* __restrict__ srz,
    float* __restrict__ h32)
{
  const int w    = threadIdx.x >> 6;
  const int lane = threadIdx.x & 63;
  const int quad = lane >> 4;
  const int lr   = lane & 15;
  const int mbase = blockIdx.x * 128 + w * 32;
  const int cbase = blockIdx.y * 128;
  const int kq = quad * 8;

  f32x4 acc[2][8];
#pragma unroll
  for (int i = 0; i < 2; ++i)
#pragma unroll
    for (int j = 0; j < 8; ++j) acc[i][j] = (f32x4){0.f, 0.f, 0.f, 0.f};

  long r0 = mbase + lr;      if (r0 >= M) r0 = M - 1;
  long r1 = mbase + 16 + lr; if (r1 >= M) r1 = M - 1;

#pragma unroll
  for (int kk = 0; kk < 4; ++kk) {
    const int kc = kk * 32 + kq;
    bf16x8 a0 = load_frag<A1F>(A1, r0, kc);
    bf16x8 a1 = load_frag<A1F>(A1, r1, kc);
#pragma unroll
    for (int ct = 0; ct < 8; ++ct) {
      const int n = cbase + ct * 16 + lr;
      bf16x8 b = *(const bf16x8*)(W1 + (size_t)n * ldw1 + kc);
      acc[0][ct] = __builtin_amdgcn_mfma_f32_16x16x32_bf16(a0, b, acc[0][ct], 0, 0, 0);
      acc[1][ct] = __builtin_amdgcn_mfma_f32_16x16x32_bf16(a1, b, acc[1][ct], 0, 0, 0);
    }
  }
  if (A2 != nullptr) {
#pragma unroll
    for (int kk = 0; kk < 4; ++kk) {
      const int kc = kk * 32 + kq;
      bf16x8 a0 = load_frag<A2F>(A2, r0, kc);
      bf16x8 a1 = load_frag<A2F>(A2, r1, kc);
#pragma unroll
      for (int ct = 0; ct < 8; ++ct) {
        const int n = cbase + ct * 16 + lr;
        bf16x8 b = *(const bf16x8*)(W2 + (size_t)n * ldw2 + kc);
        acc[0][ct] = __builtin_amdgcn_mfma_f32_16x16x32_bf16(a0, b, acc[0][ct], 0, 0, 0);
        acc[1][ct] = __builtin_amdgcn_mfma_f32_16x16x32_bf16(a1, b, acc[1][ct], 0, 0, 0);
      }
    }
  }

  // C/D layout: col = lane&15, row(within 16) = quad*4 + reg  [m89-verified]
#pragma unroll
  for (int ct = 0; ct < 8; ++ct) {
    const int n = cbase + ct * 16 + lr;
    float bv = 0.f;
    if (bias1) bv += (float)bias1[n];
    if (bias2) bv += (float)bias2[n];
#pragma unroll
    for (int rt = 0; rt < 2; ++rt) {
#pragma unroll
      for (int r = 0; r < 4; ++r) {
        const int row = mbase + rt * 16 + quad * 4 + r;
        if (row < M) {
          float v = acc[rt][ct][r] + bv;
          if constexpr (EPI == 0) {
            C[(size_t)row * ldc + n] = (bf16)v;
          } else {
            float nn = tanhf(v + (float)tmp[(size_t)row * 128 + n]);
            float z  = 1.f / (1.f + expf(-(float)srz[(size_t)row * 256 + 128 + n]));
            size_t hi = (size_t)row * 128 + n;
            h32[hi] = (1.f - z) * nn + z * h32[hi];
          }
        }
      }
    }
  }
}

// ---------------------------------------------------------------------------
// dtype detect: bf16 data never has exponent >= 0x87 (|x|>=256) in this
// problem; fp32 data misread as bf16 has ~23% such elements (low halves).
// ---------------------------------------------------------------------------
__global__ __launch_bounds__(256) void detect_k(const unsigned short* __restrict__ f,
                                                int n16, int* __restrict__ flag)
{
  int i = blockIdx.x * 256 + threadIdx.x;
  int bad = 0;
  for (int j = i; j < n16; j += 256 * 1024) {
    int ex = (f[j] >> 7) & 0xFF;
    if (ex >= 0x87) bad = 1;
  }
  if (bad) atomicAdd(flag, 1);
}

// features -> canonical bf16 + fp32 h
__global__ __launch_bounds__(256) void feat_k(const void* __restrict__ src,
                                              bf16* __restrict__ fb, float* __restrict__ h32,
                                              int n, const int* __restrict__ flag)
{
  int i = blockIdx.x * 256 + threadIdx.x;
  if (i >= n) return;
  if (*flag) { float v = ((const float*)src)[i]; fb[i] = (bf16)v; h32[i] = v; }
  else       { bf16 v = ((const bf16*)src)[i];  fb[i] = v; h32[i] = (float)v; }
}

// all 10 weight/bias arrays -> one canonical bf16 blob
__global__ __launch_bounds__(256) void cvtw_k(
    const void* s0, const void* s1, const void* s2, const void* s3, const void* s4,
    const void* s5, const void* s6, const void* s7, const void* s8, const void* s9,
    bf16* __restrict__ wb, const int* __restrict__ flag)
{
  const int sizes[10] = {65536, 512, 49152, 384, 49152, 384, 32768, 128, 16384, 128};
  const void* ptrs[10] = {s0, s1, s2, s3, s4, s5, s6, s7, s8, s9};
  int i = blockIdx.x * 256 + threadIdx.x;
  if (i >= 214528) return;
  int seg = 0, off = i;
  while (seg < 10 && off >= sizes[seg]) { off -= sizes[seg]; ++seg; }
  if (seg >= 10) return;
  if (*flag) wb[i] = (bf16)((const float*)ptrs[seg])[off];
  else       wb[i] = ((const bf16*)ptrs[seg])[off];
}

// ---------------------------------------------------------------------------
// CSR keyed by dst*2 + (etype>>1)  (2 etype-pairs -> 2 aggregate passes)
// ---------------------------------------------------------------------------
__global__ __launch_bounds__(256) void hist_k(const int* __restrict__ dst,
                                              const int* __restrict__ ety,
                                              int* __restrict__ deg, int E)
{
  int e = blockIdx.x * 256 + threadIdx.x;
  if (e < E) atomicAdd(&deg[dst[e] * 2 + (ety[e] >> 1)], 1);
}

__global__ __launch_bounds__(256) void scan1_k(const int* __restrict__ deg, int* __restrict__ rp,
                                               int* __restrict__ part, int n)
{
  __shared__ int buf[256];
  int i = blockIdx.x * 256 + threadIdx.x;
  int v = (i < n) ? deg[i] : 0;
  buf[threadIdx.x] = v;
  __syncthreads();
#pragma unroll
  for (int off = 1; off < 256; off <<= 1) {
    int t = 0;
    if (threadIdx.x >= off) t = buf[threadIdx.x - off];
    __syncthreads();
    buf[threadIdx.x] += t;
    __syncthreads();
  }
  if (i < n) rp[i] = buf[threadIdx.x] - v;
  if (threadIdx.x == 255) part[blockIdx.x] = buf[255];
}

__global__ __launch_bounds__(1024) void scan2_k(int* __restrict__ part, int nb, int* __restrict__ total)
{
  __shared__ int buf[1024];
  int t0 = threadIdx.x;
  int v = (t0 < nb) ? part[t0] : 0;
  buf[t0] = v;
  __syncthreads();
#pragma unroll
  for (int off = 1; off < 1024; off <<= 1) {
    int t = 0;
    if (t0 >= off) t = buf[t0 - off];
    __syncthreads();
    buf[t0] += t;
    __syncthreads();
  }
  if (t0 < nb) part[t0] = buf[t0] - v;
  if (t0 == 1023) *total = buf[1023];
}

__global__ __launch_bounds__(256) void scan3_k(int* __restrict__ rp, const int* __restrict__ part, int n)
{
  int i = blockIdx.x * 256 + threadIdx.x;
  if (i < n) rp[i] += part[blockIdx.x];
}

__global__ __launch_bounds__(256) void fill_k(const int* __restrict__ src, const int* __restrict__ dst,
                                              const int* __restrict__ ety, const int* __restrict__ rp,
                                              int* __restrict__ fil, int* __restrict__ bucket,
                                              int E, int N)
{
  int e = blockIdx.x * 256 + threadIdx.x;
  if (e < E) {
    int key = dst[e] * 2 + (ety[e] >> 1);
    int pos = rp[key] + atomicAdd(&fil[key], 1);
    bucket[pos] = (ety[e] & 1) * N + src[e];
  }
}

// wave per node; lane owns 2 dims; pass p sums t2 rows for etype-pair p.
__global__ __launch_bounds__(256) void agg_k(
    const bf16* __restrict__ t2, const int* __restrict__ rp,
    const int* __restrict__ bucket, bf16* __restrict__ a, int N, int pass)
{
  const int lane = threadIdx.x & 63;
  const int n = blockIdx.x * 4 + (threadIdx.x >> 6);
  if (n >= N) return;
  const int s = rp[n * 2 + pass];
  const int e = rp[n * 2 + pass + 1];
  float a0 = 0.f, a1 = 0.f;
  const unsigned int* tp = (const unsigned int*)t2;
  for (int i = s; i < e; ++i) {
    unsigned int v = tp[(size_t)bucket[i] * 64 + lane];
    union { unsigned int u; bf16 b[2]; } uu; uu.u = v;
    a0 += (float)uu.b[0];
    a1 += (float)uu.b[1];
  }
  unsigned int* ap = (unsigned int*)a;
  size_t oi = (size_t)n * 64 + lane;
  if (pass > 0) {
    union { unsigned int u; bf16 b[2]; } pu; pu.u = ap[oi];
    a0 += (float)pu.b[0];
    a1 += (float)pu.b[1];
  }
  union { unsigned int u; bf16 b[2]; } oo;
  oo.b[0] = (bf16)a0;
  oo.b[1] = (bf16)a1;
  ap[oi] = oo.u;
}

// tmp = sigmoid(srz[:, 0:128]) * hn   (in-place over hn buffer)
__global__ __launch_bounds__(256) void rz_k(const bf16* __restrict__ srz,
                                            bf16* __restrict__ hn, int total)
{
  int i = blockIdx.x * 256 + threadIdx.x;
  if (i >= total) return;
  int n = i >> 7, d = i & 127;
  float r = 1.f / (1.f + expf(-(float)srz[(size_t)n * 256 + d]));
  hn[i] = (bf16)(r * (float)hn[i]);
}

__global__ __launch_bounds__(256) void head_k(const bf16* __restrict__ gl, const bf16* __restrict__ u,
                                              void* __restrict__ out, int total,
                                              const int* __restrict__ flag)
{
  int i = blockIdx.x * 256 + threadIdx.x;
  if (i >= total) return;
  float g = 1.f / (1.f + expf(-(float)gl[i]));
  float v = g * (float)u[i];
  if (*flag) ((float*)out)[i] = v;
  else       ((bf16*)out)[i] = (bf16)v;
}

// ---------------------------------------------------------------------------
extern "C" void kernel_launch(void* const* d_in, const int* in_sizes, int n_in,
                              void* d_out, int out_size, void* d_ws, size_t ws_size,
                              hipStream_t stream)
{
  const void* feat = d_in[0];
  const int*  src  = (const int*)d_in[1];
  const int*  dst  = (const int*)d_in[2];
  const int*  ety  = (const int*)d_in[3];

  const int N = in_sizes[0] / 128;   // 100000
  const int E = in_sizes[1];         // 1600000
  const int total = N * 128;

  // ---- workspace carve-up (~163 MB) ----
  char* p = (char*)d_ws;
  auto alloc = [&](size_t bytes) -> char* {
    char* q = p;
    p += (bytes + 255) & ~(size_t)255;
    return q;
  };
  float* h32   = (float*)alloc((size_t)total * 4);          // 51.2 MB
  bf16*  S     = (bf16*) alloc((size_t)N * 256 * 2);        // 51.2 MB (t2 / srz / gl+u)
  bf16*  hnnB  = (bf16*) alloc((size_t)total * 2);          // 25.6 MB (hn / tmp)
  bf16*  featb = (bf16*) alloc((size_t)total * 2);          // 25.6 MB
  bf16*  wb    = (bf16*) alloc(214528 * 2);                 // 0.43 MB
  int*   deg   = (int*)  alloc((size_t)2 * N * 4);
  int*   fil   = (int*)  alloc((size_t)2 * N * 4);
  int*   rp    = (int*)  alloc(((size_t)2 * N + 1) * 4);
  int*   part  = (int*)  alloc(1024 * 4);
  int*   bkt   = (int*)  alloc((size_t)E * 4);
  int*   flag  = (int*)  alloc(64);
  bf16*  a     = (bf16*)d_out;                              // N*128 bf16, dead before head

  // wb element offsets
  const int oWet = 0, oBet = 65536, oWih = 66048, oBih = 115200,
            oWhh = 115584, oBhh = 164736, oIw = 165120, oIb = 197888,
            oJw = 198016, oJb = 214400;

  const int gE  = (E + 255) / 256;
  const int gT  = (total + 255) / 256;
  const int gM  = (N + 127) / 128;
  const int gN2 = (2 * N + 255) / 256;
  const int gAg = (N + 3) / 4;

  // ---- dtype detect + canonicalize ----
  hipMemsetAsync(flag, 0, 4, stream);
  detect_k<<<1024, 256, 0, stream>>>((const unsigned short*)feat, 2000000, flag);
  feat_k<<<gT, 256, 0, stream>>>(feat, featb, h32, total, flag);
  cvtw_k<<<(214528 + 255) / 256, 256, 0, stream>>>(
      d_in[4], d_in[5], d_in[6], d_in[7], d_in[8],
      d_in[9], d_in[10], d_in[11], d_in[12], d_in[13], wb, flag);

  // ---- CSR build (dst/etype constant across steps) ----
  hipMemsetAsync(deg, 0, (size_t)2 * N * 4, stream);
  hipMemsetAsync(fil, 0, (size_t)2 * N * 4, stream);
  hist_k<<<gE, 256, 0, stream>>>(dst, ety, deg, E);
  scan1_k<<<gN2, 256, 0, stream>>>(deg, rp, part, 2 * N);
  scan2_k<<<1, 1024, 0, stream>>>(part, gN2, rp + 2 * N);
  scan3_k<<<gN2, 256, 0, stream>>>(rp, part, 2 * N);
  fill_k<<<gE, 256, 0, stream>>>(src, dst, ety, rp, fil, bkt, E, N);

  for (int step = 0; step < 3; ++step) {
    // (a)+(b): two etype-pair passes; t2 = S (2 x [N,128])
    for (int pass = 0; pass < 2; ++pass) {
      for (int half = 0; half < 2; ++half) {
        int k = pass * 2 + half;
        gemm_k<true, false, 0><<<dim3(gM, 1), 256, 0, stream>>>(
            h32, wb + oWet + (size_t)k * 16384, 128,
            nullptr, nullptr, 0,
            wb + oBet + k * 128, nullptr,
            S + (size_t)half * N * 128, 128, N, nullptr, nullptr, nullptr);
      }
      agg_k<<<gAg, 256, 0, stream>>>(S, rp, bkt, a, N, pass);
    }
    // (c) GRU: hn = h@W_hh[256:]^T + b_hh[256:]
    gemm_k<true, false, 0><<<dim3(gM, 1), 256, 0, stream>>>(
        h32, wb + oWhh + 256 * 128, 128, nullptr, nullptr, 0,
        wb + oBhh + 256, nullptr, hnnB, 128, N, nullptr, nullptr, nullptr);
    // srz = a@W_ih[0:256]^T + h@W_hh[0:256]^T + b_ih + b_hh
    gemm_k<false, true, 0><<<dim3(gM, 2), 256, 0, stream>>>(
        a, wb + oWih, 128, h32, wb + oWhh, 128,
        wb + oBih, wb + oBhh, S, 256, N, nullptr, nullptr, nullptr);
    // tmp = sigmoid(r) * hn
    rz_k<<<gT, 256, 0, stream>>>(S, hnnB, total);
    // fused finish: h = (1-z)*tanh(a@W_ih[256:]^T + b_ih[256:] + tmp) + z*h
    gemm_k<false, false, 1><<<dim3(gM, 1), 256, 0, stream>>>(
        a, wb + oWih + 256 * 128, 128, nullptr, nullptr, 0,
        wb + oBih + 256, nullptr, nullptr, 128, N, hnnB, S, h32);
  }

  // ---- head ----
  gemm_k<true, false, 0><<<dim3(gM, 1), 256, 0, stream>>>(
      h32, wb + oIw, 256, featb, wb + oIw + 128, 256,
      wb + oIb, nullptr, S, 128, N, nullptr, nullptr, nullptr);
  // (A2 bf16 path) gl dual GEMM: second operand is featb (bf16)
  // NOTE: template args <true,false> give A2 the bf16 loader, which is correct.
  gemm_k<true, false, 0><<<dim3(gM, 1), 256, 0, stream>>>(
      h32, wb + oJw, 128, nullptr, nullptr, 0,
      wb + oJb, nullptr, S + (size_t)N * 128, 128, N, nullptr, nullptr, nullptr);
  head_k<<<gT, 256, 0, stream>>>(S, S + (size_t)N * 128, d_out, total, flag);
}

// Round 3
// 1572.471 us; speedup vs baseline: 1.3341x; 1.3341x over previous
//
#include <hip/hip_runtime.h>
#include <hip/hip_bf16.h>

typedef __bf16 bf16;
typedef __attribute__((ext_vector_type(8))) __bf16 bf16x8;
typedef __attribute__((ext_vector_type(4))) float f32x4;

union BP { unsigned u; bf16 b[2]; };

// ---------------------------------------------------------------------------
// Desc: one 128-output-col GEMM slice.  C[:, coff:coff+128] =
//   A1 @ swz(W1)^T (+ A2 @ swz(W2)^T) + b1 (+ b2)
// W pointers are PRE-SWIZZLED blocks: elem ((kk*8+ct)*64+lane)*8+j holds
// W[ct*16+(lane&15)][kk*32+(lane>>4)*8+j]  -> every B-load is a coalesced
// 1KB wave load.  a2mode: 0=none, 1=bf16, 2=dtype per *flagp (f32 if set).
// ---------------------------------------------------------------------------
struct Desc {
  const void* A1; const bf16* W1; int lda1;
  const void* A2; const bf16* W2; int lda2;
  const bf16* b1; const bf16* b2;
  int coff; int a2mode;
};
struct Desc4 { Desc d[4]; };

// NK = number of 32-wide K chunks (4 -> K=128, 17 -> K=544)
template<int NK>
__global__ __launch_bounds__(256) void gemm_k(Desc4 P, bf16* __restrict__ C, int ldc,
                                              int M, const int* __restrict__ flagp)
{
  const Desc d = P.d[blockIdx.y];
  const int lane = threadIdx.x & 63;
  const int w    = threadIdx.x >> 6;
  const int quad = lane >> 4;
  const int lr   = lane & 15;
  const int mbase = blockIdx.x * 128 + w * 32;

  __shared__ bf16 lds[128 * 136];   // padded stride 136 (272B rows, 16B aligned)

  f32x4 acc[2][8];
#pragma unroll
  for (int i = 0; i < 2; ++i)
#pragma unroll
    for (int j = 0; j < 8; ++j) acc[i][j] = (f32x4){0.f, 0.f, 0.f, 0.f};

  long r0 = mbase + lr;      if (r0 >= M) r0 = M - 1;
  long r1 = mbase + 16 + lr; if (r1 >= M) r1 = M - 1;

  // ---- A1 pass (A1 is always bf16) ----
  {
    const bf16* A = (const bf16*)d.A1;
    const int lda = d.lda1;
#pragma unroll
    for (int kk = 0; kk < NK; ++kk) {
      const int kc = kk * 32 + quad * 8;
      bf16x8 a0 = *(const bf16x8*)(A + r0 * lda + kc);
      bf16x8 a1 = *(const bf16x8*)(A + r1 * lda + kc);
#pragma unroll
      for (int ct = 0; ct < 8; ++ct) {
        bf16x8 b = *(const bf16x8*)(d.W1 + ((size_t)(kk * 8 + ct) * 64 + lane) * 8);
        acc[0][ct] = __builtin_amdgcn_mfma_f32_16x16x32_bf16(a0, b, acc[0][ct], 0, 0, 0);
        acc[1][ct] = __builtin_amdgcn_mfma_f32_16x16x32_bf16(a1, b, acc[1][ct], 0, 0, 0);
      }
    }
  }
  // ---- A2 pass ----
  if (d.a2mode != 0) {
    const int lda = d.lda2;
    const bool f32 = (d.a2mode == 2) && (*flagp != 0);
    if (f32) {
      const float* A = (const float*)d.A2;
#pragma unroll
      for (int kk = 0; kk < NK; ++kk) {
        const int kc = kk * 32 + quad * 8;
        f32x4 x0 = *(const f32x4*)(A + r0 * lda + kc);
        f32x4 x1 = *(const f32x4*)(A + r0 * lda + kc + 4);
        f32x4 y0 = *(const f32x4*)(A + r1 * lda + kc);
        f32x4 y1 = *(const f32x4*)(A + r1 * lda + kc + 4);
        bf16x8 a0, a1;
#pragma unroll
        for (int i = 0; i < 4; ++i) {
          a0[i] = (bf16)x0[i]; a0[i + 4] = (bf16)x1[i];
          a1[i] = (bf16)y0[i]; a1[i + 4] = (bf16)y1[i];
        }
#pragma unroll
        for (int ct = 0; ct < 8; ++ct) {
          bf16x8 b = *(const bf16x8*)(d.W2 + ((size_t)(kk * 8 + ct) * 64 + lane) * 8);
          acc[0][ct] = __builtin_amdgcn_mfma_f32_16x16x32_bf16(a0, b, acc[0][ct], 0, 0, 0);
          acc[1][ct] = __builtin_amdgcn_mfma_f32_16x16x32_bf16(a1, b, acc[1][ct], 0, 0, 0);
        }
      }
    } else {
      const bf16* A = (const bf16*)d.A2;
#pragma unroll
      for (int kk = 0; kk < NK; ++kk) {
        const int kc = kk * 32 + quad * 8;
        bf16x8 a0 = *(const bf16x8*)(A + r0 * lda + kc);
        bf16x8 a1 = *(const bf16x8*)(A + r1 * lda + kc);
#pragma unroll
        for (int ct = 0; ct < 8; ++ct) {
          bf16x8 b = *(const bf16x8*)(d.W2 + ((size_t)(kk * 8 + ct) * 64 + lane) * 8);
          acc[0][ct] = __builtin_amdgcn_mfma_f32_16x16x32_bf16(a0, b, acc[0][ct], 0, 0, 0);
          acc[1][ct] = __builtin_amdgcn_mfma_f32_16x16x32_bf16(a1, b, acc[1][ct], 0, 0, 0);
        }
      }
    }
  }

  // ---- epilogue: acc -> LDS (C/D layout: col=lr, row16 = quad*4+reg) ----
#pragma unroll
  for (int ct = 0; ct < 8; ++ct) {
    const int nl = ct * 16 + lr;
    float bv = 0.f;
    if (d.b1) bv += (float)d.b1[nl];
    if (d.b2) bv += (float)d.b2[nl];
#pragma unroll
    for (int rt = 0; rt < 2; ++rt) {
      const int rowb = w * 32 + rt * 16 + quad * 4;
#pragma unroll
      for (int r = 0; r < 4; ++r)
        lds[(rowb + r) * 136 + nl] = (bf16)(acc[rt][ct][r] + bv);
    }
  }
  __syncthreads();
  // coalesced readback + store: 16 threads cover one 256B row segment
  const int tr = threadIdx.x >> 4;          // 0..15
  const int tc = (threadIdx.x & 15) * 8;    // col
#pragma unroll
  for (int i = 0; i < 8; ++i) {
    const int row = i * 16 + tr;
    const int grow = blockIdx.x * 128 + row;
    if (grow < M) {
      bf16x8 v = *(const bf16x8*)(lds + row * 136 + tc);
      *(bf16x8*)(C + (size_t)grow * ldc + d.coff + tc) = v;
    }
  }
}

// ---------------------------------------------------------------------------
// dtype detect (bf16 features never have |x|>=256; fp32 low halves do)
// ---------------------------------------------------------------------------
__global__ __launch_bounds__(256) void detect_k(const unsigned short* __restrict__ f,
                                                int n16, int* __restrict__ flag)
{
  int i = blockIdx.x * 256 + threadIdx.x;
  int bad = 0;
  for (int j = i; j < n16; j += 256 * 1024) {
    int ex = (f[j] >> 7) & 0xFF;
    if (ex >= 0x87) bad = 1;
  }
  if (bad) atomicAdd(flag, 1);
}

__global__ __launch_bounds__(256) void feat_k(const void* __restrict__ src,
                                              bf16* __restrict__ hb, int n,
                                              const int* __restrict__ flag)
{
  int i = blockIdx.x * 256 + threadIdx.x;
  if (i >= n) return;
  if (*flag) hb[i] = (bf16)((const float*)src)[i];
  else       hb[i] = ((const bf16*)src)[i];
}

// ---------------------------------------------------------------------------
// weight canonicalize + swizzle.  wb layout (elements):
//   [0, 69632)        WcatX swz, NK=17: (n,k): k<512 -> W_et[k>>7][n][k&127],
//                     512..515 -> b_et[k-512][n], else 0
//   [69632 + blk*16384) 9 swz 128x128 blocks: ih0,ih1,ihn,hh0,hh1,hhn,iwa,iwb,jw
//   [217088) b_ih(384) b_hh(384) i_b(128) j_b(128)   -> total 218112
// ---------------------------------------------------------------------------
__global__ __launch_bounds__(256) void cvtw_k(
    const void* w_et, const void* b_et, const void* w_ih, const void* b_ih,
    const void* w_hh, const void* b_hh, const void* i_w, const void* i_b,
    const void* j_w, const void* j_b, bf16* __restrict__ wb,
    const int* __restrict__ flagp)
{
  int i = blockIdx.x * 256 + threadIdx.x;
  if (i >= 218112) return;
  const bool f32 = (*flagp != 0);
  auto rd = [&](const void* p, int idx) -> float {
    return f32 ? ((const float*)p)[idx] : (float)((const bf16*)p)[idx];
  };
  float v;
  if (i < 69632) {
    int e = i, j = e & 7, lane = (e >> 3) & 63, ct = (e >> 9) & 7, kk = e >> 12;
    int n = ct * 16 + (lane & 15), k = kk * 32 + (lane >> 4) * 8 + j;
    if (k < 512)      v = rd(w_et, (k >> 7) * 16384 + n * 128 + (k & 127));
    else if (k < 516) v = rd(b_et, (k - 512) * 128 + n);
    else              v = 0.f;
  } else if (i < 217088) {
    int blk = (i - 69632) >> 14, e = (i - 69632) & 16383;
    int j = e & 7, lane = (e >> 3) & 63, ct = (e >> 9) & 7, kk = e >> 12;
    int n = ct * 16 + (lane & 15), k = kk * 32 + (lane >> 4) * 8 + j;
    const void* src; int idx;
    switch (blk) {
      case 0: src = w_ih; idx = n * 128 + k; break;
      case 1: src = w_ih; idx = (128 + n) * 128 + k; break;
      case 2: src = w_ih; idx = (256 + n) * 128 + k; break;
      case 3: src = w_hh; idx = n * 128 + k; break;
      case 4: src = w_hh; idx = (128 + n) * 128 + k; break;
      case 5: src = w_hh; idx = (256 + n) * 128 + k; break;
      case 6: src = i_w;  idx = n * 256 + k; break;
      case 7: src = i_w;  idx = n * 256 + 128 + k; break;
      default: src = j_w; idx = n * 128 + k; break;
    }
    v = rd(src, idx);
  } else {
    int o = i - 217088;
    if (o < 384)      v = rd(b_ih, o);
    else if (o < 768) v = rd(b_hh, o - 384);
    else if (o < 896) v = rd(i_b, o - 768);
    else              v = rd(j_b, o - 896);
  }
  wb[i] = (bf16)v;
}

// ---------------------------------------------------------------------------
// CSR keyed by dst*4 + etype  (dst/etype constant across steps)
// ---------------------------------------------------------------------------
__global__ __launch_bounds__(256) void hist_k(const int* __restrict__ dst,
                                              const int* __restrict__ ety,
                                              int* __restrict__ deg, int E)
{
  int e = blockIdx.x * 256 + threadIdx.x;
  if (e < E) atomicAdd(&deg[dst[e] * 4 + ety[e]], 1);
}

__global__ __launch_bounds__(512) void scan1_k(const int* __restrict__ deg, int* __restrict__ rp,
                                               int* __restrict__ part, int n)
{
  __shared__ int buf[512];
  int i = blockIdx.x * 512 + threadIdx.x;
  int v = (i < n) ? deg[i] : 0;
  buf[threadIdx.x] = v;
  __syncthreads();
#pragma unroll
  for (int off = 1; off < 512; off <<= 1) {
    int t = 0;
    if (threadIdx.x >= off) t = buf[threadIdx.x - off];
    __syncthreads();
    buf[threadIdx.x] += t;
    __syncthreads();
  }
  if (i < n) rp[i] = buf[threadIdx.x] - v;
  if (threadIdx.x == 511) part[blockIdx.x] = buf[511];
}

__global__ __launch_bounds__(1024) void scan2_k(int* __restrict__ part, int nb, int* __restrict__ total)
{
  __shared__ int buf[1024];
  int t0 = threadIdx.x;
  int v = (t0 < nb) ? part[t0] : 0;
  buf[t0] = v;
  __syncthreads();
#pragma unroll
  for (int off = 1; off < 1024; off <<= 1) {
    int t = 0;
    if (t0 >= off) t = buf[t0 - off];
    __syncthreads();
    buf[t0] += t;
    __syncthreads();
  }
  if (t0 < nb) part[t0] = buf[t0] - v;
  if (t0 == 1023) *total = buf[1023];
}

__global__ __launch_bounds__(512) void scan3_k(int* __restrict__ rp, const int* __restrict__ part, int n)
{
  int i = blockIdx.x * 512 + threadIdx.x;
  if (i < n) rp[i] += part[blockIdx.x];
}

__global__ __launch_bounds__(256) void fill_k(const int* __restrict__ src, const int* __restrict__ dst,
                                              const int* __restrict__ ety, const int* __restrict__ rp,
                                              int* __restrict__ fil, int* __restrict__ bkt, int E)
{
  int e = blockIdx.x * 256 + threadIdx.x;
  if (e < E) {
    int key = dst[e] * 4 + ety[e];
    int pos = rp[key] + atomicAdd(&fil[key], 1);
    bkt[pos] = src[e];
  }
}

// ---------------------------------------------------------------------------
// aggregate raw h per (dst, etype) -> aggH[n, 544]:
//   cols k*128+d = sum of h[src][d] over etype-k in-edges; 512+k = deg_k; rest 0
// wave per node; lane owns 2 dims (one dword per edge-row read)
// ---------------------------------------------------------------------------
__global__ __launch_bounds__(256) void agg_k(const bf16* __restrict__ hb,
                                             const int* __restrict__ rp,
                                             const int* __restrict__ bkt,
                                             bf16* __restrict__ aggH, int N)
{
  const int lane = threadIdx.x & 63;
  const int n = blockIdx.x * 4 + (threadIdx.x >> 6);
  if (n >= N) return;
  const unsigned* hp = (const unsigned*)hb;
  unsigned* outp = (unsigned*)aggH + (size_t)n * 272;
  int d0, d1, d2, d3;
  int prev = rp[n * 4];
#pragma unroll
  for (int k = 0; k < 4; ++k) {
    int nxt = rp[n * 4 + k + 1];
    float a0 = 0.f, a1 = 0.f;
    for (int i = prev; i < nxt; ++i) {
      BP u; u.u = hp[(size_t)bkt[i] * 64 + lane];
      a0 += (float)u.b[0];
      a1 += (float)u.b[1];
    }
    BP o; o.b[0] = (bf16)a0; o.b[1] = (bf16)a1;
    outp[k * 64 + lane] = o.u;
    int dk = nxt - prev;
    if (k == 0) d0 = dk; else if (k == 1) d1 = dk; else if (k == 2) d2 = dk; else d3 = dk;
    prev = nxt;
  }
  if (lane < 16) {
    BP o; o.b[0] = (bf16)0.f; o.b[1] = (bf16)0.f;
    if (lane == 0) { o.b[0] = (bf16)(float)d0; o.b[1] = (bf16)(float)d1; }
    if (lane == 1) { o.b[0] = (bf16)(float)d2; o.b[1] = (bf16)(float)d3; }
    outp[256 + lane] = o.u;
  }
}

// ---------------------------------------------------------------------------
// GRU finish: G[n,512] = [srz(256) | in(128) | hn(128)];  h' -> hb (bf16)
// ---------------------------------------------------------------------------
__global__ __launch_bounds__(256) void gru_k(const bf16* __restrict__ G,
                                             bf16* __restrict__ hb, int N)
{
  int i = blockIdx.x * 256 + threadIdx.x;    // over N*64 (bf16x2 per thread)
  if (i >= N * 64) return;
  int n = i >> 6, l = i & 63;
  const unsigned* g = (const unsigned*)G + (size_t)n * 256;
  unsigned* h = (unsigned*)hb + (size_t)n * 64;
  BP sr, sz, in_, hn, hv, o;
  sr.u = g[l]; sz.u = g[64 + l]; in_.u = g[128 + l]; hn.u = g[192 + l];
  hv.u = h[l];
#pragma unroll
  for (int q = 0; q < 2; ++q) {
    float r = 1.f / (1.f + expf(-(float)sr.b[q]));
    float z = 1.f / (1.f + expf(-(float)sz.b[q]));
    float nn = tanhf((float)in_.b[q] + r * (float)hn.b[q]);
    o.b[q] = (bf16)((1.f - z) * nn + z * (float)hv.b[q]);
  }
  h[l] = o.u;
}

// head: G[n,256] = [gl | u];  out = sigmoid(gl) * u
__global__ __launch_bounds__(256) void head_k(const bf16* __restrict__ G,
                                              void* __restrict__ out, int N,
                                              const int* __restrict__ flag)
{
  int i = blockIdx.x * 256 + threadIdx.x;    // over N*64
  if (i >= N * 64) return;
  int n = i >> 6, l = i & 63;
  const unsigned* g = (const unsigned*)G + (size_t)n * 128;
  BP gl, uu;
  gl.u = g[l]; uu.u = g[64 + l];
  float v0 = (float)uu.b[0] / (1.f + expf(-(float)gl.b[0]));
  float v1 = (float)uu.b[1] / (1.f + expf(-(float)gl.b[1]));
  if (*flag) {
    ((float*)out)[(size_t)n * 128 + 2 * l]     = v0;
    ((float*)out)[(size_t)n * 128 + 2 * l + 1] = v1;
  } else {
    BP o; o.b[0] = (bf16)v0; o.b[1] = (bf16)v1;
    ((unsigned*)out)[(size_t)n * 64 + l] = o.u;
  }
}

// ---------------------------------------------------------------------------
extern "C" void kernel_launch(void* const* d_in, const int* in_sizes, int n_in,
                              void* d_out, int out_size, void* d_ws, size_t ws_size,
                              hipStream_t stream)
{
  const void* feat = d_in[0];
  const int*  src  = (const int*)d_in[1];
  const int*  dst  = (const int*)d_in[2];
  const int*  ety  = (const int*)d_in[3];

  const int N = in_sizes[0] / 128;   // 100000
  const int E = in_sizes[1];         // 1600000
  const int total = N * 128;

  // ---- workspace (~145 MB) ----
  char* p = (char*)d_ws;
  auto alloc = [&](size_t bytes) -> char* {
    char* q = p;
    p += (bytes + 255) & ~(size_t)255;
    return q;
  };
  bf16* big  = (bf16*)alloc((size_t)N * 544 * 2);   // aggH [N,544] / G [N,512]
  bf16* hb   = (bf16*)alloc((size_t)total * 2);     // h (bf16)
  bf16* wb   = (bf16*)alloc(218112 * 2);
  int*  rp   = (int*) alloc(((size_t)4 * N + 1) * 4);
  int*  deg  = (int*) alloc((size_t)4 * N * 4);     // reused as fill counters
  int*  bkt  = (int*) alloc((size_t)E * 4);
  int*  part = (int*) alloc(1024 * 4);
  int*  flag = (int*) alloc(64);
  bf16* a    = (bf16*)d_out;                        // [N,128], dead before head

  // wb offsets
  const int oWcat = 0, oBlk = 69632;
  const bf16 *ih0 = wb + oBlk,            *ih1 = wb + oBlk + 16384,
             *ihn = wb + oBlk + 2 * 16384, *hh0 = wb + oBlk + 3 * 16384,
             *hh1 = wb + oBlk + 4 * 16384, *hhn = wb + oBlk + 5 * 16384,
             *iwa = wb + oBlk + 6 * 16384, *iwb = wb + oBlk + 7 * 16384,
             *jw  = wb + oBlk + 8 * 16384;
  const bf16 *bih = wb + 217088, *bhh = wb + 217472, *ib = wb + 217856,
             *jb  = wb + 217984;

  const int gE  = (E + 255) / 256;
  const int gT  = (total + 255) / 256;
  const int gM  = (N + 127) / 128;
  const int n4  = 4 * N;
  const int gS  = (n4 + 511) / 512;
  const int gH  = (N * 64 + 255) / 256;

  // ---- dtype detect + canonicalize ----
  hipMemsetAsync(flag, 0, 4, stream);
  detect_k<<<1024, 256, 0, stream>>>((const unsigned short*)feat, 2000000, flag);
  feat_k<<<gT, 256, 0, stream>>>(feat, hb, total, flag);
  cvtw_k<<<(218112 + 255) / 256, 256, 0, stream>>>(
      d_in[4], d_in[5], d_in[6], d_in[7], d_in[8],
      d_in[9], d_in[10], d_in[11], d_in[12], d_in[13], wb, flag);

  // ---- CSR build ----
  hipMemsetAsync(deg, 0, (size_t)n4 * 4, stream);
  hist_k<<<gE, 256, 0, stream>>>(dst, ety, deg, E);
  scan1_k<<<gS, 512, 0, stream>>>(deg, rp, part, n4);
  scan2_k<<<1, 1024, 0, stream>>>(part, gS, rp + n4);
  scan3_k<<<gS, 512, 0, stream>>>(rp, part, n4);
  hipMemsetAsync(deg, 0, (size_t)n4 * 4, stream);
  fill_k<<<gE, 256, 0, stream>>>(src, dst, ety, rp, deg, bkt, E);

  // ---- GEMM descriptors ----
  Desc4 Pa = {};
  Pa.d[0] = { big, wb + oWcat, 544, nullptr, nullptr, 0, nullptr, nullptr, 0, 0 };
  Desc4 Pg = {};
  Pg.d[0] = { a,  ih0, 128, hb, hh0, 128, bih,       bhh,       0,   1 };
  Pg.d[1] = { a,  ih1, 128, hb, hh1, 128, bih + 128, bhh + 128, 128, 1 };
  Pg.d[2] = { a,  ihn, 128, nullptr, nullptr, 0, bih + 256, nullptr, 256, 0 };
  Pg.d[3] = { hb, hhn, 128, nullptr, nullptr, 0, bhh + 256, nullptr, 384, 0 };
  Desc4 Ph = {};
  Ph.d[0] = { hb, iwa, 128, feat, iwb, 128, ib, nullptr, 0,   2 };
  Ph.d[1] = { hb, jw,  128, nullptr, nullptr, 0, jb, nullptr, 128, 0 };

  for (int step = 0; step < 3; ++step) {
    agg_k<<<(N + 3) / 4, 256, 0, stream>>>(hb, rp, bkt, big, N);
    gemm_k<17><<<dim3(gM, 1), 256, 0, stream>>>(Pa, a, 128, N, flag);
    gemm_k<4><<<dim3(gM, 4), 256, 0, stream>>>(Pg, big, 512, N, flag);
    gru_k<<<gH, 256, 0, stream>>>(big, hb, N);
  }

  // ---- head ----
  gemm_k<4><<<dim3(gM, 2), 256, 0, stream>>>(Ph, big, 256, N, flag);
  head_k<<<gH, 256, 0, stream>>>(big, d_out, N, flag);
}